// Round 8
// baseline (716.715 us; speedup 1.0000x reference)
//
#include <hip/hip_runtime.h>
#include <math.h>

// ---------------------------------------------------------------------------
// Phase 1: natural cubic spline coefficients, 3 channels. Single block.
// ---------------------------------------------------------------------------
__global__ void spline_setup(const float* __restrict__ delay_in,
                             const float* __restrict__ raw,
                             double* __restrict__ coef,
                             int* __restrict__ minz,
                             int nf) {
    extern __shared__ double smem[];
    double* xch = smem;           // 3*nf
    double* cp  = xch + 3 * nf;   // nf
    double* kk  = cp + nf;        // 3*nf

    int tid = threadIdx.x;
    if (tid == 0) *minz = 0x7fffffff;

    for (int i = tid; i < nf; i += blockDim.x) {
        double s0 = 1.0 / (1.0 + exp(-(double)raw[2 * i + 0]));
        double s1 = 1.0 / (1.0 + exp(-(double)raw[2 * i + 1]));
        double ss = s0 + s1;
        xch[0 * nf + i] = (double)delay_in[i];
        xch[1 * nf + i] = s0 / ss;
        xch[2 * nf + i] = s1 / ss;
    }
    __syncthreads();

    if (tid == 0) {
        cp[0] = 0.5;
        for (int i = 1; i < nf; ++i) {
            double d = (i == nf - 1) ? 2.0 : 4.0;
            cp[i] = 1.0 / (d - cp[i - 1]);
        }
    }
    __syncthreads();

    if (tid < 3) {
        const double* x = xch + tid * nf;
        double* k = kk + tid * nf;
        double hinv = (double)(nf - 1);
        double prev = 0.0;
        for (int j = 0; j < nf; ++j) {
            double r = 0.0;
            if (j < nf - 1) r += 3.0 * hinv * (x[j + 1] - x[j]);
            if (j > 0)      r += 3.0 * hinv * (x[j] - x[j - 1]);
            double dp = (r - prev) * cp[j];
            k[j] = dp;
            prev = dp;
        }
        for (int j = nf - 2; j >= 0; --j) k[j] = k[j] - cp[j] * k[j + 1];
    }
    __syncthreads();

    int nint = nf - 1;
    double hinv = (double)(nf - 1);
    for (int w = tid; w < 3 * nint; w += blockDim.x) {
        int ch = w / nint;
        int i = w - ch * nint;
        const double* x = xch + ch * nf;
        const double* k = kk + ch * nf;
        double dx3 = 3.0 * (x[i + 1] - x[i]);
        double two_c   = (2.0 * dx3 * hinv - 4.0 * k[i] - 2.0 * k[i + 1]) * hinv;
        double three_d = (-2.0 * dx3 * hinv + 3.0 * (k[i] + k[i + 1])) * hinv * hinv;
        double* C = coef + (size_t)(ch * nint + i) * 4;
        C[0] = x[i];
        C[1] = k[i];
        C[2] = 0.5 * two_c;
        C[3] = three_d * (1.0 / 3.0);
    }
}

// ---------------------------------------------------------------------------
// Phase 2: per-sample spline eval -> {g1, g2, g3, pk} one float4.
// pk packs the 3 wrapped history slots: r_i = (t - z - i) & 1023,
// pk = (r1<<20)|(r2<<10)|r3. Global min z via one atomic per wave.
// Pads [n, nTot) with zeros so the scan's deep prefetch loads unguarded.
// ---------------------------------------------------------------------------
__global__ void eval_kernel(const double* __restrict__ coef,
                            float4* __restrict__ gx,
                            int* __restrict__ minz,
                            int n, int nTot, int nf) {
    int j = blockIdx.x * blockDim.x + threadIdx.x;
    if (j >= nTot) return;
    if (j >= n) { gx[j] = make_float4(0.f, 0.f, 0.f, 0.f); return; }

    double u = (double)j / (double)(n - 1);
    double nfm1 = (double)(nf - 1);
    int idx = (int)(u * nfm1);
    if (idx > nf - 2) idx = nf - 2;
    if (idx < 0) idx = 0;
    double tknot = (double)idx / nfm1;
    if (u < tknot && idx > 0) {
        idx--; tknot = (double)idx / nfm1;
    } else {
        double tnext = (double)(idx + 1) / nfm1;
        if (u >= tnext && idx < nf - 2) { idx++; tknot = tnext; }
    }
    double f = u - tknot;

    int nint = nf - 1;
    const double* C0 = coef + (size_t)(0 * nint + idx) * 4;
    const double* C1 = coef + (size_t)(1 * nint + idx) * 4;
    const double* C2 = coef + (size_t)(2 * nint + idx) * 4;
    double dly = C0[0] + f * (C0[1] + f * (C0[2] + f * C0[3]));
    double b1d = C1[0] + f * (C1[1] + f * (C1[2] + f * C1[3]));
    double b2d = C2[0] + f * (C2[1] + f * (C2[2] + f * C2[3]));

    double zf = floor(dly);
    int z = (int)zf;
    float alfa = (float)(dly - zf);
    float b1 = (float)b1d, b2 = (float)b2d;
    float g1 = b1 * (1.0f - alfa);
    float g2 = b1 * alfa + b2 * (1.0f - alfa);
    float g3 = b2 * alfa;

    int r1 = (j - z - 1) & 1023;
    int r2 = (j - z - 2) & 1023;
    int r3 = (j - z - 3) & 1023;
    unsigned int pk = (unsigned int)((r1 << 20) | (r2 << 10) | r3);
    gx[j] = make_float4(g1, g2, g3, __uint_as_float(pk));

    int wmin = z;
    #pragma unroll
    for (int o = 32; o > 0; o >>= 1) wmin = min(wmin, __shfl_down(wmin, o, 64));
    if ((threadIdx.x & 63) == 0) atomicMin(minz, wmin);
}

// ---------------------------------------------------------------------------
// Phase 3: wave-synchronous fixed-chunk recurrence, ONE wave, no barriers.
// gx stream prefetched K=12 chunks deep into an LDS ring via
// __builtin_amdgcn_global_load_lds (zero VGPR cost — round-6/7 post-mortem:
// the compiler refuses to materialize a register pipeline, VGPR_Count=56).
// Counted s_waitcnt vmcnt(40): every iteration issues EXACTLY 4 vmem ops
// (2 ring loads + 2 always-full-exec y stores via sink redirect), so chunk
// i+1's slot (issued 11 iterations ago, 44 ops deep) is guaranteed resident.
// Chunk i+1's stream is ds_read into regs one iteration early, keeping the
// per-iteration critical chain = history ds_read (~120cy) + FMA.
// ---------------------------------------------------------------------------
__global__ void __launch_bounds__(64, 1)
scan_kernel(const float4* __restrict__ gx,
            const int* __restrict__ minz,
            const float* __restrict__ exc,
            float* __restrict__ y,
            float* __restrict__ sink,
            int n, int burst) {
    __shared__ float buf[1026];        // 1024 circular + 2 dummy write slots
    __shared__ float excl[2048];
    __shared__ float4 ring[16 * 128];  // 16 chunk slots, 32 KB

    const int tid = threadIdx.x;
    for (int i = tid; i < 1026; i += 64) buf[i] = 0.0f;
    for (int i = tid; i < 2048; i += 64) excl[i] = (i < burst) ? exc[i] : 0.0f;
    // single wave: in-order LDS pipe, no barrier needed.

    int D = __builtin_amdgcn_readfirstlane(*minz) + 1;
    if (D > 128) D = 128;
    if (D < 4) D = 4;
    const int nIter = (n + D - 1) / D;
    const int K = 12;

#define RING_LOAD(c)                                                          \
    {                                                                         \
        int _slot = (c) & 15;                                                 \
        const float4* _g = gx + (c) * D + tid;                                \
        __builtin_amdgcn_global_load_lds(                                     \
            (const __attribute__((address_space(1))) void*)_g,                \
            (__attribute__((address_space(3))) void*)&ring[_slot * 128],      \
            16, 0, 0);                                                        \
        __builtin_amdgcn_global_load_lds(                                     \
            (const __attribute__((address_space(1))) void*)(_g + 64),         \
            (__attribute__((address_space(3))) void*)&ring[_slot * 128 + 64], \
            16, 0, 0);                                                        \
    }

    // prologue: fill ring slots 0..K-1, drain once
    for (int c = 0; c < K; ++c) RING_LOAD(c)
    asm volatile("s_waitcnt vmcnt(0)" ::: "memory");
    __builtin_amdgcn_sched_barrier(0);

    float4 qa = ring[tid];
    float4 qb = ring[64 + tid];

    for (int i = 0; i < nIter; ++i) {
        // 1. issue prefetch for chunk i+K (2 vmem ops, full exec)
        RING_LOAD(i + K)
        // 2. counted wait: chunk i+1's slot resident (44 ops deep, margin 4)
        asm volatile("s_waitcnt vmcnt(40)" ::: "memory");
        __builtin_amdgcn_sched_barrier(0);
        // 3. stream regs for chunk i+1
        int slot1 = (i + 1) & 15;
        float4 na = ring[slot1 * 128 + tid];
        float4 nb = ring[slot1 * 128 + 64 + tid];
        // 4. body for chunk i (all history reads before any buf write)
        int base = i * D;
        int t0 = base + tid;
        int t1 = t0 + 64;
        unsigned int k0 = __float_as_uint(qa.w);
        unsigned int k1 = __float_as_uint(qb.w);
        float a1 = buf[k0 >> 20];
        float a2 = buf[(k0 >> 10) & 1023];
        float a3 = buf[k0 & 1023];
        float b1 = buf[k1 >> 20];
        float b2 = buf[(k1 >> 10) & 1023];
        float b3 = buf[k1 & 1023];
        float xa = 0.0f, xb = 0.0f;
        if (base < burst) {  // chunk-uniform; taken only first ~20 chunks
            float ra = excl[t0 & 2047];
            float rb = excl[t1 & 2047];
            xa = (t0 < burst) ? ra : 0.0f;
            xb = (t1 < burst) ? rb : 0.0f;
        }
        float ya = fmaf(qa.x, a1, xa);
        ya = fmaf(qa.y, a2, ya);
        ya = fmaf(qa.z, a3, ya);
        float yb = fmaf(qb.x, b1, xb);
        yb = fmaf(qb.y, b2, yb);
        yb = fmaf(qb.z, b3, yb);
        bool ok0 = (tid < D) && (t0 < n);
        bool ok1 = (64 + tid < D) && (t1 < n);
        // LDS writes: dummy slots 1024/1025 for masked lanes (never read)
        buf[ok0 ? (t0 & 1023) : 1024] = ya;
        buf[ok1 ? (t1 & 1023) : 1025] = yb;
        // global stores: ALWAYS full-exec (sink redirect) so vmcnt count
        // per iteration is exactly 4 (2 loads + 2 stores)
        float* d0 = ok0 ? (y + t0) : (sink + tid);
        float* d1 = ok1 ? (y + t1) : (sink + 64 + tid);
        *d0 = ya;
        *d1 = yb;
        qa = na; qb = nb;
    }
#undef RING_LOAD
}

// ---------------------------------------------------------------------------
extern "C" void kernel_launch(void* const* d_in, const int* in_sizes, int n_in,
                              void* d_out, int out_size, void* d_ws, size_t ws_size,
                              hipStream_t stream) {
    const float* delay = (const float*)d_in[0];
    const float* raw   = (const float*)d_in[1];
    const float* exc   = (const float*)d_in[2];
    int nf = in_sizes[0];
    int burst = in_sizes[2];
    if (burst > 2048) burst = 2048;
    int n = out_size;
    int nTot = n + 4096;   // pad covers K=12 prefetch overshoot (<= 12*128+192)

    char* ws = (char*)d_ws;
    size_t coefBytes = (size_t)3 * (nf - 1) * 4 * sizeof(double);
    size_t off = (coefBytes + 255) & ~(size_t)255;
    double* coef = (double*)ws;
    int* minz = (int*)(ws + off);
    off += 256;
    float* sink = (float*)(ws + off);
    off += 512;
    float4* gxa = (float4*)(ws + off);

    size_t shmem = (size_t)(7 * nf) * sizeof(double);
    spline_setup<<<1, 64, shmem, stream>>>(delay, raw, coef, minz, nf);
    eval_kernel<<<(nTot + 255) / 256, 256, 0, stream>>>(coef, gxa, minz, n, nTot, nf);
    scan_kernel<<<1, 64, 0, stream>>>(gxa, minz, exc, (float*)d_out, sink, n, burst);
}

// Round 9
// 338.336 us; speedup vs baseline: 2.1184x; 2.1184x over previous
//
#include <hip/hip_runtime.h>
#include <math.h>

// ---------------------------------------------------------------------------
// Phase 1: natural cubic spline coefficients, 3 channels. Single block.
// ---------------------------------------------------------------------------
__global__ void spline_setup(const float* __restrict__ delay_in,
                             const float* __restrict__ raw,
                             double* __restrict__ coef,
                             int* __restrict__ minz,
                             int nf) {
    extern __shared__ double smem[];
    double* xch = smem;           // 3*nf
    double* cp  = xch + 3 * nf;   // nf
    double* kk  = cp + nf;        // 3*nf

    int tid = threadIdx.x;
    if (tid == 0) *minz = 0x7fffffff;

    for (int i = tid; i < nf; i += blockDim.x) {
        double s0 = 1.0 / (1.0 + exp(-(double)raw[2 * i + 0]));
        double s1 = 1.0 / (1.0 + exp(-(double)raw[2 * i + 1]));
        double ss = s0 + s1;
        xch[0 * nf + i] = (double)delay_in[i];
        xch[1 * nf + i] = s0 / ss;
        xch[2 * nf + i] = s1 / ss;
    }
    __syncthreads();

    if (tid == 0) {
        cp[0] = 0.5;
        for (int i = 1; i < nf; ++i) {
            double d = (i == nf - 1) ? 2.0 : 4.0;
            cp[i] = 1.0 / (d - cp[i - 1]);
        }
    }
    __syncthreads();

    if (tid < 3) {
        const double* x = xch + tid * nf;
        double* k = kk + tid * nf;
        double hinv = (double)(nf - 1);
        double prev = 0.0;
        for (int j = 0; j < nf; ++j) {
            double r = 0.0;
            if (j < nf - 1) r += 3.0 * hinv * (x[j + 1] - x[j]);
            if (j > 0)      r += 3.0 * hinv * (x[j] - x[j - 1]);
            double dp = (r - prev) * cp[j];
            k[j] = dp;
            prev = dp;
        }
        for (int j = nf - 2; j >= 0; --j) k[j] = k[j] - cp[j] * k[j + 1];
    }
    __syncthreads();

    int nint = nf - 1;
    double hinv = (double)(nf - 1);
    for (int w = tid; w < 3 * nint; w += blockDim.x) {
        int ch = w / nint;
        int i = w - ch * nint;
        const double* x = xch + ch * nf;
        const double* k = kk + ch * nf;
        double dx3 = 3.0 * (x[i + 1] - x[i]);
        double two_c   = (2.0 * dx3 * hinv - 4.0 * k[i] - 2.0 * k[i + 1]) * hinv;
        double three_d = (-2.0 * dx3 * hinv + 3.0 * (k[i] + k[i + 1])) * hinv * hinv;
        double* C = coef + (size_t)(ch * nint + i) * 4;
        C[0] = x[i];
        C[1] = k[i];
        C[2] = 0.5 * two_c;
        C[3] = three_d * (1.0 / 3.0);
    }
}

// ---------------------------------------------------------------------------
// Phase 2: per-sample spline eval -> {g1, g2, g3, pk} one float4.
// pk packs the 3 wrapped history slots: r_i = (t - z - i) & 1023.
// Global min z via one atomic per wave. Pads [n, nTot) with zeros.
// ---------------------------------------------------------------------------
__global__ void eval_kernel(const double* __restrict__ coef,
                            float4* __restrict__ gx,
                            int* __restrict__ minz,
                            int n, int nTot, int nf) {
    int j = blockIdx.x * blockDim.x + threadIdx.x;
    if (j >= nTot) return;
    if (j >= n) { gx[j] = make_float4(0.f, 0.f, 0.f, 0.f); return; }

    double u = (double)j / (double)(n - 1);
    double nfm1 = (double)(nf - 1);
    int idx = (int)(u * nfm1);
    if (idx > nf - 2) idx = nf - 2;
    if (idx < 0) idx = 0;
    double tknot = (double)idx / nfm1;
    if (u < tknot && idx > 0) {
        idx--; tknot = (double)idx / nfm1;
    } else {
        double tnext = (double)(idx + 1) / nfm1;
        if (u >= tnext && idx < nf - 2) { idx++; tknot = tnext; }
    }
    double f = u - tknot;

    int nint = nf - 1;
    const double* C0 = coef + (size_t)(0 * nint + idx) * 4;
    const double* C1 = coef + (size_t)(1 * nint + idx) * 4;
    const double* C2 = coef + (size_t)(2 * nint + idx) * 4;
    double dly = C0[0] + f * (C0[1] + f * (C0[2] + f * C0[3]));
    double b1d = C1[0] + f * (C1[1] + f * (C1[2] + f * C1[3]));
    double b2d = C2[0] + f * (C2[1] + f * (C2[2] + f * C2[3]));

    double zf = floor(dly);
    int z = (int)zf;
    float alfa = (float)(dly - zf);
    float b1 = (float)b1d, b2 = (float)b2d;
    float g1 = b1 * (1.0f - alfa);
    float g2 = b1 * alfa + b2 * (1.0f - alfa);
    float g3 = b2 * alfa;

    int r1 = (j - z - 1) & 1023;
    int r2 = (j - z - 2) & 1023;
    int r3 = (j - z - 3) & 1023;
    unsigned int pk = (unsigned int)((r1 << 20) | (r2 << 10) | r3);
    gx[j] = make_float4(g1, g2, g3, __uint_as_float(pk));

    int wmin = z;
    #pragma unroll
    for (int o = 32; o > 0; o >>= 1) wmin = min(wmin, __shfl_down(wmin, o, 64));
    if ((threadIdx.x & 63) == 0) atomicMin(minz, wmin);
}

// ---------------------------------------------------------------------------
// Phase 3: producer/consumer 2-wave recurrence (round-8 post-mortem: a single
// wave cannot keep vmem latency off its own critical path — the compiler
// drains its async loads; so give vmem latency to a DIFFERENT wave).
// Wave 1 (producer): per group of 8 chunks, 16 global_load_dwordx4 -> regs ->
// 16 ds_write_b128 into a double-buffered LDS ring. Its vmcnt stalls never
// block the consumer.
// Wave 0 (consumer): per group, 16 ds_read_b128 (stream regs, issued up
// front) + 8 serial chunk bodies; critical chain = history ds_read + 3 FMA +
// ds_write. Zero vmem on the path (y stores fire-and-forget).
// One __syncthreads() per group; buffers alternate: producer writes (g+1)&1
// while consumer reads g&1; consumer's stream reads for group g+1 issue only
// after the barrier -> no race.
// Chunk size D = min(z)+1 in [4,128]; all history reads of a chunk target
// positions < base, so per-body reads-then-writes is correct, and the
// single-wave in-order LDS pipe orders chunk i before chunk i+1.
// ---------------------------------------------------------------------------
__global__ void __launch_bounds__(128, 1)
scan_kernel(const float4* __restrict__ gx,
            const int* __restrict__ minz,
            const float* __restrict__ exc,
            float* __restrict__ y,
            int n, int burst) {
    __shared__ float buf[1026];        // 1024 circular + 2 dummy write slots
    __shared__ float excl[2048];
    __shared__ float4 ring[2 * 8 * 128];  // 2 groups x 8 chunks x 128, 32 KB

    const int tid = threadIdx.x;
    for (int i = tid; i < 1026; i += 128) buf[i] = 0.0f;
    for (int i = tid; i < 2048; i += 128) excl[i] = (i < burst) ? exc[i] : 0.0f;
    __syncthreads();

    int D = __builtin_amdgcn_readfirstlane(*minz) + 1;
    if (D > 128) D = 128;
    if (D < 4) D = 4;
    const int nIter = (n + D - 1) / D;
    const int nG = (nIter + 7) >> 3;

#define PRODUCE(p8, wb)                                                       \
    {                                                                         \
        int lane = tid - 64;                                                  \
        float4 l0a = gx[(p8 + 0) * D + lane];                                 \
        float4 l0b = gx[(p8 + 0) * D + 64 + lane];                            \
        float4 l1a = gx[(p8 + 1) * D + lane];                                 \
        float4 l1b = gx[(p8 + 1) * D + 64 + lane];                            \
        float4 l2a = gx[(p8 + 2) * D + lane];                                 \
        float4 l2b = gx[(p8 + 2) * D + 64 + lane];                            \
        float4 l3a = gx[(p8 + 3) * D + lane];                                 \
        float4 l3b = gx[(p8 + 3) * D + 64 + lane];                            \
        float4 l4a = gx[(p8 + 4) * D + lane];                                 \
        float4 l4b = gx[(p8 + 4) * D + 64 + lane];                            \
        float4 l5a = gx[(p8 + 5) * D + lane];                                 \
        float4 l5b = gx[(p8 + 5) * D + 64 + lane];                            \
        float4 l6a = gx[(p8 + 6) * D + lane];                                 \
        float4 l6b = gx[(p8 + 6) * D + 64 + lane];                            \
        float4 l7a = gx[(p8 + 7) * D + lane];                                 \
        float4 l7b = gx[(p8 + 7) * D + 64 + lane];                            \
        ring[(wb) + 0 * 128 + lane] = l0a;                                    \
        ring[(wb) + 0 * 128 + 64 + lane] = l0b;                               \
        ring[(wb) + 1 * 128 + lane] = l1a;                                    \
        ring[(wb) + 1 * 128 + 64 + lane] = l1b;                               \
        ring[(wb) + 2 * 128 + lane] = l2a;                                    \
        ring[(wb) + 2 * 128 + 64 + lane] = l2b;                               \
        ring[(wb) + 3 * 128 + lane] = l3a;                                    \
        ring[(wb) + 3 * 128 + 64 + lane] = l3b;                               \
        ring[(wb) + 4 * 128 + lane] = l4a;                                    \
        ring[(wb) + 4 * 128 + 64 + lane] = l4b;                               \
        ring[(wb) + 5 * 128 + lane] = l5a;                                    \
        ring[(wb) + 5 * 128 + 64 + lane] = l5b;                               \
        ring[(wb) + 6 * 128 + lane] = l6a;                                    \
        ring[(wb) + 6 * 128 + 64 + lane] = l6b;                               \
        ring[(wb) + 7 * 128 + lane] = l7a;                                    \
        ring[(wb) + 7 * 128 + 64 + lane] = l7b;                               \
    }

#define CBODY(qa, qb, c)                                                      \
    {                                                                         \
        int base = (g8 + (c)) * D;                                            \
        int t0 = base + tid;                                                  \
        int t1 = t0 + 64;                                                     \
        unsigned int k0 = __float_as_uint((qa).w);                            \
        unsigned int k1 = __float_as_uint((qb).w);                            \
        float a1 = buf[k0 >> 20];                                             \
        float a2 = buf[(k0 >> 10) & 1023];                                    \
        float a3 = buf[k0 & 1023];                                            \
        float b1 = buf[k1 >> 20];                                             \
        float b2 = buf[(k1 >> 10) & 1023];                                    \
        float b3 = buf[k1 & 1023];                                            \
        float xa = 0.0f, xb = 0.0f;                                           \
        if (base < burst) {                                                   \
            float ra = excl[t0 & 2047];                                       \
            float rb = excl[t1 & 2047];                                       \
            xa = (t0 < burst) ? ra : 0.0f;                                    \
            xb = (t1 < burst) ? rb : 0.0f;                                    \
        }                                                                     \
        float ya = fmaf((qa).x, a1, xa);                                      \
        ya = fmaf((qa).y, a2, ya);                                            \
        ya = fmaf((qa).z, a3, ya);                                            \
        float yb = fmaf((qb).x, b1, xb);                                      \
        yb = fmaf((qb).y, b2, yb);                                            \
        yb = fmaf((qb).z, b3, yb);                                            \
        bool ok0 = (tid < D) && (t0 < n);                                     \
        bool ok1 = (64 + tid < D) && (t1 < n);                                \
        buf[ok0 ? (t0 & 1023) : 1024] = ya;                                   \
        buf[ok1 ? (t1 & 1023) : 1025] = yb;                                   \
        if (ok0) y[t0] = ya;                                                  \
        if (ok1) y[t1] = yb;                                                  \
    }

    // prologue: producer fills group 0 into ring buffer 0
    if (tid >= 64) PRODUCE(0, 0)
    __syncthreads();

    for (int g = 0; g < nG; ++g) {
        if (tid >= 64) {
            int p8 = (g + 1) * 8;
            int wb = ((g + 1) & 1) << 10;
            PRODUCE(p8, wb)
        } else {
            int g8 = g * 8;
            int rb = (g & 1) << 10;
            float4 q0a = ring[rb + 0 * 128 + tid];
            float4 q0b = ring[rb + 0 * 128 + 64 + tid];
            float4 q1a = ring[rb + 1 * 128 + tid];
            float4 q1b = ring[rb + 1 * 128 + 64 + tid];
            float4 q2a = ring[rb + 2 * 128 + tid];
            float4 q2b = ring[rb + 2 * 128 + 64 + tid];
            float4 q3a = ring[rb + 3 * 128 + tid];
            float4 q3b = ring[rb + 3 * 128 + 64 + tid];
            float4 q4a = ring[rb + 4 * 128 + tid];
            float4 q4b = ring[rb + 4 * 128 + 64 + tid];
            float4 q5a = ring[rb + 5 * 128 + tid];
            float4 q5b = ring[rb + 5 * 128 + 64 + tid];
            float4 q6a = ring[rb + 6 * 128 + tid];
            float4 q6b = ring[rb + 6 * 128 + 64 + tid];
            float4 q7a = ring[rb + 7 * 128 + tid];
            float4 q7b = ring[rb + 7 * 128 + 64 + tid];
            CBODY(q0a, q0b, 0)
            CBODY(q1a, q1b, 1)
            CBODY(q2a, q2b, 2)
            CBODY(q3a, q3b, 3)
            CBODY(q4a, q4b, 4)
            CBODY(q5a, q5b, 5)
            CBODY(q6a, q6b, 6)
            CBODY(q7a, q7b, 7)
        }
        __syncthreads();
    }
#undef PRODUCE
#undef CBODY
}

// ---------------------------------------------------------------------------
extern "C" void kernel_launch(void* const* d_in, const int* in_sizes, int n_in,
                              void* d_out, int out_size, void* d_ws, size_t ws_size,
                              hipStream_t stream) {
    const float* delay = (const float*)d_in[0];
    const float* raw   = (const float*)d_in[1];
    const float* exc   = (const float*)d_in[2];
    int nf = in_sizes[0];
    int burst = in_sizes[2];
    if (burst > 2048) burst = 2048;
    int n = out_size;
    int nTot = n + 4096;   // pad covers producer overshoot (<= 15*128 + 192)

    char* ws = (char*)d_ws;
    size_t coefBytes = (size_t)3 * (nf - 1) * 4 * sizeof(double);
    size_t off = (coefBytes + 255) & ~(size_t)255;
    double* coef = (double*)ws;
    int* minz = (int*)(ws + off);
    off += 256;
    float4* gxa = (float4*)(ws + off);

    size_t shmem = (size_t)(7 * nf) * sizeof(double);
    spline_setup<<<1, 64, shmem, stream>>>(delay, raw, coef, minz, nf);
    eval_kernel<<<(nTot + 255) / 256, 256, 0, stream>>>(coef, gxa, minz, n, nTot, nf);
    scan_kernel<<<1, 128, 0, stream>>>(gxa, minz, exc, (float*)d_out, n, burst);
}

// Round 10
// 336.947 us; speedup vs baseline: 2.1271x; 1.0041x over previous
//
#include <hip/hip_runtime.h>
#include <math.h>

// ---------------------------------------------------------------------------
// Phase 1: natural cubic spline coefficients, 3 channels. Single block.
// ---------------------------------------------------------------------------
__global__ void spline_setup(const float* __restrict__ delay_in,
                             const float* __restrict__ raw,
                             double* __restrict__ coef,
                             int* __restrict__ minz,
                             int nf) {
    extern __shared__ double smem[];
    double* xch = smem;           // 3*nf
    double* cp  = xch + 3 * nf;   // nf
    double* kk  = cp + nf;        // 3*nf

    int tid = threadIdx.x;
    if (tid == 0) *minz = 0x7fffffff;

    for (int i = tid; i < nf; i += blockDim.x) {
        double s0 = 1.0 / (1.0 + exp(-(double)raw[2 * i + 0]));
        double s1 = 1.0 / (1.0 + exp(-(double)raw[2 * i + 1]));
        double ss = s0 + s1;
        xch[0 * nf + i] = (double)delay_in[i];
        xch[1 * nf + i] = s0 / ss;
        xch[2 * nf + i] = s1 / ss;
    }
    __syncthreads();

    if (tid == 0) {
        cp[0] = 0.5;
        for (int i = 1; i < nf; ++i) {
            double d = (i == nf - 1) ? 2.0 : 4.0;
            cp[i] = 1.0 / (d - cp[i - 1]);
        }
    }
    __syncthreads();

    if (tid < 3) {
        const double* x = xch + tid * nf;
        double* k = kk + tid * nf;
        double hinv = (double)(nf - 1);
        double prev = 0.0;
        for (int j = 0; j < nf; ++j) {
            double r = 0.0;
            if (j < nf - 1) r += 3.0 * hinv * (x[j + 1] - x[j]);
            if (j > 0)      r += 3.0 * hinv * (x[j] - x[j - 1]);
            double dp = (r - prev) * cp[j];
            k[j] = dp;
            prev = dp;
        }
        for (int j = nf - 2; j >= 0; --j) k[j] = k[j] - cp[j] * k[j + 1];
    }
    __syncthreads();

    int nint = nf - 1;
    double hinv = (double)(nf - 1);
    for (int w = tid; w < 3 * nint; w += blockDim.x) {
        int ch = w / nint;
        int i = w - ch * nint;
        const double* x = xch + ch * nf;
        const double* k = kk + ch * nf;
        double dx3 = 3.0 * (x[i + 1] - x[i]);
        double two_c   = (2.0 * dx3 * hinv - 4.0 * k[i] - 2.0 * k[i + 1]) * hinv;
        double three_d = (-2.0 * dx3 * hinv + 3.0 * (k[i] + k[i + 1])) * hinv * hinv;
        double* C = coef + (size_t)(ch * nint + i) * 4;
        C[0] = x[i];
        C[1] = k[i];
        C[2] = 0.5 * two_c;
        C[3] = three_d * (1.0 / 3.0);
    }
}

// ---------------------------------------------------------------------------
// Phase 2: per-sample spline eval -> {g1, g2, g3, s3} one float4.
// s3 = (t - z - 3) & 2047 : base slot of the 3 contiguous history reads
// (slots s3, s3+1, s3+2; slots 2048/2049 shadow 0/1 in the scan buffer).
// Global min z via one atomic per wave. Pads [n, nTot) with zeros.
// ---------------------------------------------------------------------------
__global__ void eval_kernel(const double* __restrict__ coef,
                            float4* __restrict__ gx,
                            int* __restrict__ minz,
                            int n, int nTot, int nf) {
    int j = blockIdx.x * blockDim.x + threadIdx.x;
    if (j >= nTot) return;
    if (j >= n) { gx[j] = make_float4(0.f, 0.f, 0.f, 0.f); return; }

    double u = (double)j / (double)(n - 1);
    double nfm1 = (double)(nf - 1);
    int idx = (int)(u * nfm1);
    if (idx > nf - 2) idx = nf - 2;
    if (idx < 0) idx = 0;
    double tknot = (double)idx / nfm1;
    if (u < tknot && idx > 0) {
        idx--; tknot = (double)idx / nfm1;
    } else {
        double tnext = (double)(idx + 1) / nfm1;
        if (u >= tnext && idx < nf - 2) { idx++; tknot = tnext; }
    }
    double f = u - tknot;

    int nint = nf - 1;
    const double* C0 = coef + (size_t)(0 * nint + idx) * 4;
    const double* C1 = coef + (size_t)(1 * nint + idx) * 4;
    const double* C2 = coef + (size_t)(2 * nint + idx) * 4;
    double dly = C0[0] + f * (C0[1] + f * (C0[2] + f * C0[3]));
    double b1d = C1[0] + f * (C1[1] + f * (C1[2] + f * C1[3]));
    double b2d = C2[0] + f * (C2[1] + f * (C2[2] + f * C2[3]));

    double zf = floor(dly);
    int z = (int)zf;
    float alfa = (float)(dly - zf);
    float b1 = (float)b1d, b2 = (float)b2d;
    float g1 = b1 * (1.0f - alfa);
    float g2 = b1 * alfa + b2 * (1.0f - alfa);
    float g3 = b2 * alfa;

    int s3 = (j - z - 3) & 2047;
    gx[j] = make_float4(g1, g2, g3, __uint_as_float((unsigned int)s3));

    int wmin = z;
    #pragma unroll
    for (int o = 32; o > 0; o >>= 1) wmin = min(wmin, __shfl_down(wmin, o, 64));
    if ((threadIdx.x & 63) == 0) atomicMin(minz, wmin);
}

// ---------------------------------------------------------------------------
// Phase 3: producer/consumer 2-wave recurrence.
// Round-9 post-mortem: register-staged producer got serialized (VGPR=88 <
// the 128 needed) -> use global_load_lds (zero staging regs, all 16 loads
// in flight, one vmcnt drain per group on the producer wave only).
// Wave 1 (producer), per group g: (1) 16 global_load_lds -> ring half
// (g+1)&1 for group g+1; (2) y-offload of group g-1: ds_read buf slots,
// global_store y (fills its own vmcnt wait); __syncthreads drains vmcnt.
// Wave 0 (consumer): PURE LDS - 16 stream ds_read_b128 + 8 chunk bodies
// (history ds_read ~120cy + 3 FMA + masked ds_write); zero vmem ops, so
// its barrier drain is free.
// buf = 2048 circular + 2 shadow (mirror slots 0/1 for contiguous s3..s3+2
// reads) + 2 dummy (masked-lane writes). Clobber distance 2048 > 2 group
// spans (16*128) => producer reading group g-1 never races consumer
// writing group g.
// Chunk size D = min(z)+1 in [4,128]; all history reads of a chunk target
// positions < base; single-wave in-order LDS pipe orders chunk i before
// chunk i+1.
// ---------------------------------------------------------------------------
__global__ void __launch_bounds__(128, 1)
scan_kernel(const float4* __restrict__ gx,
            const int* __restrict__ minz,
            const float* __restrict__ exc,
            float* __restrict__ y,
            int n, int burst) {
    __shared__ float buf[2052];           // 2048 circular + 2 shadow + 2 dummy
    __shared__ float excl[2048];
    __shared__ float4 ring[2 * 8 * 128];  // 2 halves x 8 chunks x 128, 32 KB

    const int tid = threadIdx.x;
    for (int i = tid; i < 2052; i += 128) buf[i] = 0.0f;
    for (int i = tid; i < 2048; i += 128) excl[i] = (i < burst) ? exc[i] : 0.0f;
    __syncthreads();

    int D = __builtin_amdgcn_readfirstlane(*minz) + 1;
    if (D > 128) D = 128;
    if (D < 4) D = 4;
    const int nIter = (n + D - 1) / D;
    const int nG = (nIter + 7) >> 3;

#define PRODUCE(cbase, wb)                                                    \
    {                                                                         \
        _Pragma("unroll")                                                     \
        for (int c = 0; c < 8; ++c) {                                         \
            const float4* _s = gx + ((cbase) + c) * D + lane;                 \
            __builtin_amdgcn_global_load_lds(                                 \
                (const __attribute__((address_space(1))) void*)_s,            \
                (__attribute__((address_space(3))) void*)&ring[(wb) + c * 128], \
                16, 0, 0);                                                    \
            __builtin_amdgcn_global_load_lds(                                 \
                (const __attribute__((address_space(1))) void*)(_s + 64),     \
                (__attribute__((address_space(3))) void*)&ring[(wb) + c * 128 + 64], \
                16, 0, 0);                                                    \
        }                                                                     \
    }

#define CBODY(qa, qb, c)                                                      \
    {                                                                         \
        int base = (g8 + (c)) * D;                                            \
        int t0 = base + tid;                                                  \
        int t1 = t0 + 64;                                                     \
        unsigned int s0 = __float_as_uint((qa).w);                            \
        unsigned int s1 = __float_as_uint((qb).w);                            \
        float a3 = buf[s0];                                                   \
        float a2 = buf[s0 + 1];                                               \
        float a1 = buf[s0 + 2];                                               \
        float b3 = buf[s1];                                                   \
        float b2 = buf[s1 + 1];                                               \
        float b1 = buf[s1 + 2];                                               \
        float xa = 0.0f, xb = 0.0f;                                           \
        if (base < burst) {                                                   \
            float ra = excl[t0 & 2047];                                       \
            float rb = excl[t1 & 2047];                                       \
            xa = (t0 < burst) ? ra : 0.0f;                                    \
            xb = (t1 < burst) ? rb : 0.0f;                                    \
        }                                                                     \
        float ya = fmaf((qa).x, a1, xa);                                      \
        ya = fmaf((qa).y, a2, ya);                                            \
        ya = fmaf((qa).z, a3, ya);                                            \
        float yb = fmaf((qb).x, b1, xb);                                      \
        yb = fmaf((qb).y, b2, yb);                                            \
        yb = fmaf((qb).z, b3, yb);                                            \
        bool ok0 = (tid < D) && (t0 < n);                                     \
        bool ok1 = (64 + tid < D) && (t1 < n);                                \
        int w0 = t0 & 2047;                                                   \
        int w1 = t1 & 2047;                                                   \
        buf[ok0 ? w0 : 2050] = ya;                                            \
        buf[ok1 ? w1 : 2051] = yb;                                            \
        if (ok0 && w0 < 2) buf[2048 + w0] = ya;                               \
        if (ok1 && w1 < 2) buf[2048 + w1] = yb;                               \
    }

    // prologue: producer fills group 0 into ring half 0
    if (tid >= 64) {
        int lane = tid - 64;
        PRODUCE(0, 0)
    }
    __syncthreads();   // drains producer's vmcnt -> group 0 resident

    for (int g = 0; g < nG; ++g) {
        if (tid >= 64) {
            int lane = tid - 64;
            // (1) prefetch group g+1 (async, zero registers)
            PRODUCE((g + 1) * 8, ((g + 1) & 1) << 10)
            // (2) y-offload of group g-1 (fills the vmcnt wait)
            if (g > 0) {
                int start = (g - 1) * 8 * D;
                int cnt = 8 * D;
                float vals[16];
                #pragma unroll
                for (int k = 0; k < 16; ++k) {
                    int t = start + k * 64 + lane;
                    vals[k] = buf[t & 2047];
                }
                #pragma unroll
                for (int k = 0; k < 16; ++k) {
                    int off = k * 64 + lane;
                    int t = start + off;
                    if (off < cnt && t < n) y[t] = vals[k];
                }
            }
        } else {
            int g8 = g * 8;
            int rb = (g & 1) << 10;
            float4 q0a = ring[rb + 0 * 128 + tid];
            float4 q0b = ring[rb + 0 * 128 + 64 + tid];
            float4 q1a = ring[rb + 1 * 128 + tid];
            float4 q1b = ring[rb + 1 * 128 + 64 + tid];
            float4 q2a = ring[rb + 2 * 128 + tid];
            float4 q2b = ring[rb + 2 * 128 + 64 + tid];
            float4 q3a = ring[rb + 3 * 128 + tid];
            float4 q3b = ring[rb + 3 * 128 + 64 + tid];
            float4 q4a = ring[rb + 4 * 128 + tid];
            float4 q4b = ring[rb + 4 * 128 + 64 + tid];
            float4 q5a = ring[rb + 5 * 128 + tid];
            float4 q5b = ring[rb + 5 * 128 + 64 + tid];
            float4 q6a = ring[rb + 6 * 128 + tid];
            float4 q6b = ring[rb + 6 * 128 + 64 + tid];
            float4 q7a = ring[rb + 7 * 128 + tid];
            float4 q7b = ring[rb + 7 * 128 + 64 + tid];
            CBODY(q0a, q0b, 0)
            CBODY(q1a, q1b, 1)
            CBODY(q2a, q2b, 2)
            CBODY(q3a, q3b, 3)
            CBODY(q4a, q4b, 4)
            CBODY(q5a, q5b, 5)
            CBODY(q6a, q6b, 6)
            CBODY(q7a, q7b, 7)
        }
        __syncthreads();
    }

    // epilogue: offload the last group's outputs (all 128 threads)
    {
        int start = (nG - 1) * 8 * D;
        for (int t = start + tid; t < n; t += 128) y[t] = buf[t & 2047];
    }
#undef PRODUCE
#undef CBODY
}

// ---------------------------------------------------------------------------
extern "C" void kernel_launch(void* const* d_in, const int* in_sizes, int n_in,
                              void* d_out, int out_size, void* d_ws, size_t ws_size,
                              hipStream_t stream) {
    const float* delay = (const float*)d_in[0];
    const float* raw   = (const float*)d_in[1];
    const float* exc   = (const float*)d_in[2];
    int nf = in_sizes[0];
    int burst = in_sizes[2];
    if (burst > 2048) burst = 2048;
    int n = out_size;
    int nTot = n + 4096;   // pad covers producer prefetch overshoot (<= 2 group spans)

    char* ws = (char*)d_ws;
    size_t coefBytes = (size_t)3 * (nf - 1) * 4 * sizeof(double);
    size_t off = (coefBytes + 255) & ~(size_t)255;
    double* coef = (double*)ws;
    int* minz = (int*)(ws + off);
    off += 256;
    float4* gxa = (float4*)(ws + off);

    size_t shmem = (size_t)(7 * nf) * sizeof(double);
    spline_setup<<<1, 64, shmem, stream>>>(delay, raw, coef, minz, nf);
    eval_kernel<<<(nTot + 255) / 256, 256, 0, stream>>>(coef, gxa, minz, n, nTot, nf);
    scan_kernel<<<1, 128, 0, stream>>>(gxa, minz, exc, (float*)d_out, n, burst);
}

// Round 11
// 306.745 us; speedup vs baseline: 2.3365x; 1.0985x over previous
//
#include <hip/hip_runtime.h>
#include <math.h>

// ---------------------------------------------------------------------------
// Phase 1: natural cubic spline coefficients, 3 channels. Single block.
// ---------------------------------------------------------------------------
__global__ void spline_setup(const float* __restrict__ delay_in,
                             const float* __restrict__ raw,
                             double* __restrict__ coef,
                             int* __restrict__ minz,
                             int nf) {
    extern __shared__ double smem[];
    double* xch = smem;           // 3*nf
    double* cp  = xch + 3 * nf;   // nf
    double* kk  = cp + nf;        // 3*nf

    int tid = threadIdx.x;
    if (tid == 0) *minz = 0x7fffffff;

    for (int i = tid; i < nf; i += blockDim.x) {
        double s0 = 1.0 / (1.0 + exp(-(double)raw[2 * i + 0]));
        double s1 = 1.0 / (1.0 + exp(-(double)raw[2 * i + 1]));
        double ss = s0 + s1;
        xch[0 * nf + i] = (double)delay_in[i];
        xch[1 * nf + i] = s0 / ss;
        xch[2 * nf + i] = s1 / ss;
    }
    __syncthreads();

    if (tid == 0) {
        cp[0] = 0.5;
        for (int i = 1; i < nf; ++i) {
            double d = (i == nf - 1) ? 2.0 : 4.0;
            cp[i] = 1.0 / (d - cp[i - 1]);
        }
    }
    __syncthreads();

    if (tid < 3) {
        const double* x = xch + tid * nf;
        double* k = kk + tid * nf;
        double hinv = (double)(nf - 1);
        double prev = 0.0;
        for (int j = 0; j < nf; ++j) {
            double r = 0.0;
            if (j < nf - 1) r += 3.0 * hinv * (x[j + 1] - x[j]);
            if (j > 0)      r += 3.0 * hinv * (x[j] - x[j - 1]);
            double dp = (r - prev) * cp[j];
            k[j] = dp;
            prev = dp;
        }
        for (int j = nf - 2; j >= 0; --j) k[j] = k[j] - cp[j] * k[j + 1];
    }
    __syncthreads();

    int nint = nf - 1;
    double hinv = (double)(nf - 1);
    for (int w = tid; w < 3 * nint; w += blockDim.x) {
        int ch = w / nint;
        int i = w - ch * nint;
        const double* x = xch + ch * nf;
        const double* k = kk + ch * nf;
        double dx3 = 3.0 * (x[i + 1] - x[i]);
        double two_c   = (2.0 * dx3 * hinv - 4.0 * k[i] - 2.0 * k[i + 1]) * hinv;
        double three_d = (-2.0 * dx3 * hinv + 3.0 * (k[i] + k[i + 1])) * hinv * hinv;
        double* C = coef + (size_t)(ch * nint + i) * 4;
        C[0] = x[i];
        C[1] = k[i];
        C[2] = 0.5 * two_c;
        C[3] = three_d * (1.0 / 3.0);
    }
}

// ---------------------------------------------------------------------------
// Phase 2: per-sample spline eval -> {g1, g2, g3, s3} one float4.
// s3 = (t - z - 3) & 2047 : base slot of the 3 contiguous history reads
// (slots s3..s3+2; slots 2048/2049 shadow 0/1 in the scan buffer).
// Global min z via one atomic per wave. Pads [n, nTot) with zeros.
// ---------------------------------------------------------------------------
__global__ void eval_kernel(const double* __restrict__ coef,
                            float4* __restrict__ gx,
                            int* __restrict__ minz,
                            int n, int nTot, int nf) {
    int j = blockIdx.x * blockDim.x + threadIdx.x;
    if (j >= nTot) return;
    if (j >= n) { gx[j] = make_float4(0.f, 0.f, 0.f, 0.f); return; }

    double u = (double)j / (double)(n - 1);
    double nfm1 = (double)(nf - 1);
    int idx = (int)(u * nfm1);
    if (idx > nf - 2) idx = nf - 2;
    if (idx < 0) idx = 0;
    double tknot = (double)idx / nfm1;
    if (u < tknot && idx > 0) {
        idx--; tknot = (double)idx / nfm1;
    } else {
        double tnext = (double)(idx + 1) / nfm1;
        if (u >= tnext && idx < nf - 2) { idx++; tknot = tnext; }
    }
    double f = u - tknot;

    int nint = nf - 1;
    const double* C0 = coef + (size_t)(0 * nint + idx) * 4;
    const double* C1 = coef + (size_t)(1 * nint + idx) * 4;
    const double* C2 = coef + (size_t)(2 * nint + idx) * 4;
    double dly = C0[0] + f * (C0[1] + f * (C0[2] + f * C0[3]));
    double b1d = C1[0] + f * (C1[1] + f * (C1[2] + f * C1[3]));
    double b2d = C2[0] + f * (C2[1] + f * (C2[2] + f * C2[3]));

    double zf = floor(dly);
    int z = (int)zf;
    float alfa = (float)(dly - zf);
    float b1 = (float)b1d, b2 = (float)b2d;
    float g1 = b1 * (1.0f - alfa);
    float g2 = b1 * alfa + b2 * (1.0f - alfa);
    float g3 = b2 * alfa;

    int s3 = (j - z - 3) & 2047;
    gx[j] = make_float4(g1, g2, g3, __uint_as_float((unsigned int)s3));

    int wmin = z;
    #pragma unroll
    for (int o = 32; o > 0; o >>= 1) wmin = min(wmin, __shfl_down(wmin, o, 64));
    if ((threadIdx.x & 63) == 0) atomicMin(minz, wmin);
}

// ---------------------------------------------------------------------------
// Phase 3: producer/consumer with T4 counted-vmcnt pipeline.
// Round-10 post-mortem: __syncthreads' mandatory vmcnt(0) drain serialized
// the producer's cold gx loads (~900-1300cy) into EVERY group. Fix: raw
// s_barrier + counted s_waitcnt vmcnt(32); producer prefetches group g+2
// into a 4-deep ring, so each group's loads get 2 full group-times to land.
// Per group the producer issues EXACTLY 16 stores (y-offload of group g-1,
// dummies to sink for g=0) then 16 global_load_lds; at the wait, ops newer
// than group g+1's loads = 16+16 = 32 -> vmcnt(32) guarantees g+1 resident
// (m135 semantics: waits for oldest beyond N).
// Consumer: pure LDS, branchless (cndmask'd dummy slots), hoisted masks,
// no n-checks in the main loop (full groups only; tail handled after).
// buf = 2048 circular + 2 shadow (mirror 0/1) + 2 dummy.
// ---------------------------------------------------------------------------
__global__ void __launch_bounds__(128, 1)
scan_kernel(const float4* __restrict__ gx,
            const int* __restrict__ minz,
            const float* __restrict__ exc,
            float* __restrict__ y,
            float* __restrict__ sink,
            int n, int burst) {
    __shared__ float buf[2052];            // 2048 circular + 2 shadow + 2 dummy
    __shared__ float excl[2048];
    __shared__ float4 ring[4 * 8 * 128];   // 4 group-slots x 8 chunks x 128 = 64 KB

    const int tid = threadIdx.x;
    for (int i = tid; i < 2052; i += 128) buf[i] = 0.0f;
    for (int i = tid; i < 2048; i += 128) excl[i] = (i < burst) ? exc[i] : 0.0f;

    int D = __builtin_amdgcn_readfirstlane(*minz) + 1;
    if (D > 128) D = 128;
    if (D < 4) D = 4;
    const int nIter = (n + D - 1) / D;
    const int span = 8 * D;                // samples per group
    const int nFull = n / span;            // fully-interior groups

#define PRODUCE(cbase, wslot)                                                 \
    {                                                                         \
        _Pragma("unroll")                                                     \
        for (int c = 0; c < 8; ++c) {                                         \
            const float4* _s = gx + ((cbase) + c) * D + lane;                 \
            __builtin_amdgcn_global_load_lds(                                 \
                (const __attribute__((address_space(1))) void*)_s,            \
                (__attribute__((address_space(3))) void*)&ring[(wslot) * 1024 + c * 128], \
                16, 0, 0);                                                    \
            __builtin_amdgcn_global_load_lds(                                 \
                (const __attribute__((address_space(1))) void*)(_s + 64),     \
                (__attribute__((address_space(3))) void*)&ring[(wslot) * 1024 + c * 128 + 64], \
                16, 0, 0);                                                    \
        }                                                                     \
    }

    // consumer body, full-group fast path (no n-checks; masks hoisted)
#define CBODY(qa, qb, c)                                                      \
    {                                                                         \
        int base = gbase + (c) * D;                                           \
        int t0 = base + tid;                                                  \
        int t1 = t0 + 64;                                                     \
        unsigned int s0 = __float_as_uint((qa).w);                            \
        unsigned int s1 = __float_as_uint((qb).w);                            \
        float a3 = buf[s0];                                                   \
        float a2 = buf[s0 + 1];                                               \
        float a1 = buf[s0 + 2];                                               \
        float b3 = buf[s1];                                                   \
        float b2 = buf[s1 + 1];                                               \
        float b1 = buf[s1 + 2];                                               \
        float xa = 0.0f, xb = 0.0f;                                           \
        if (base < burst) {                                                   \
            float ra = excl[t0 & 2047];                                       \
            float rb = excl[t1 & 2047];                                       \
            xa = (t0 < burst) ? ra : 0.0f;                                    \
            xb = (t1 < burst) ? rb : 0.0f;                                    \
        }                                                                     \
        float ya = fmaf((qa).x, a1, xa);                                      \
        ya = fmaf((qa).y, a2, ya);                                            \
        ya = fmaf((qa).z, a3, ya);                                            \
        float yb = fmaf((qb).x, b1, xb);                                      \
        yb = fmaf((qb).y, b2, yb);                                            \
        yb = fmaf((qb).z, b3, yb);                                            \
        int w0 = t0 & 2047;                                                   \
        int w1 = t1 & 2047;                                                   \
        buf[on0 ? w0 : 2050] = ya;                                            \
        buf[on1 ? w1 : 2051] = yb;                                            \
        buf[(on0 && w0 < 2) ? 2048 + w0 : 2050] = ya;                         \
        buf[(on1 && w1 < 2) ? 2048 + w1 : 2051] = yb;                         \
    }

    // prologue: fill ring slots 0,1 (groups 0,1); full drain once.
    if (tid >= 64) {
        int lane = tid - 64;
        PRODUCE(0, 0)
        PRODUCE(8, 1)
    }
    __syncthreads();

    const bool on0 = (tid < D);
    const bool on1 = (64 + tid < D);

    for (int g = 0; g < nFull; ++g) {
        if (tid >= 64) {
            int lane = tid - 64;
            // (1) exactly 16 stores: y-offload of group g-1 (dummies for g=0)
            int startPrev = (g - 1) * span;
            bool real = (g > 0);
            float vals[16];
            #pragma unroll
            for (int k = 0; k < 16; ++k)
                vals[k] = buf[(startPrev + k * 64 + lane) & 2047];
            #pragma unroll
            for (int k = 0; k < 16; ++k) {
                int off = k * 64 + lane;
                bool ok = real && (off < span);
                float* dst = ok ? (y + startPrev + off) : (sink + off);
                *dst = vals[k];
            }
            // (2) exactly 16 loads: prefetch group g+2
            PRODUCE((g + 2) * 8, (g + 2) & 3)
            // (3) counted wait: group g+1's loads (32 ops back) resident
            asm volatile("s_waitcnt vmcnt(32)" ::: "memory");
        } else {
            int gbase = g * span;
            int rb = (g & 3) << 10;
            float4 q0a = ring[rb + 0 * 128 + tid];
            float4 q0b = ring[rb + 0 * 128 + 64 + tid];
            float4 q1a = ring[rb + 1 * 128 + tid];
            float4 q1b = ring[rb + 1 * 128 + 64 + tid];
            float4 q2a = ring[rb + 2 * 128 + tid];
            float4 q2b = ring[rb + 2 * 128 + 64 + tid];
            float4 q3a = ring[rb + 3 * 128 + tid];
            float4 q3b = ring[rb + 3 * 128 + 64 + tid];
            float4 q4a = ring[rb + 4 * 128 + tid];
            float4 q4b = ring[rb + 4 * 128 + 64 + tid];
            float4 q5a = ring[rb + 5 * 128 + tid];
            float4 q5b = ring[rb + 5 * 128 + 64 + tid];
            float4 q6a = ring[rb + 6 * 128 + tid];
            float4 q6b = ring[rb + 6 * 128 + 64 + tid];
            float4 q7a = ring[rb + 7 * 128 + tid];
            float4 q7b = ring[rb + 7 * 128 + 64 + tid];
            CBODY(q0a, q0b, 0)
            CBODY(q1a, q1b, 1)
            CBODY(q2a, q2b, 2)
            CBODY(q3a, q3b, 3)
            CBODY(q4a, q4b, 4)
            CBODY(q5a, q5b, 5)
            CBODY(q6a, q6b, 6)
            CBODY(q7a, q7b, 7)
        }
        // raw barrier: producer's g+2 loads stay in flight across it (T4)
        asm volatile("s_waitcnt lgkmcnt(0)" ::: "memory");
        __builtin_amdgcn_sched_barrier(0);
        __builtin_amdgcn_s_barrier();
        __builtin_amdgcn_sched_barrier(0);
    }

    // full drain + barrier before epilogue/tail
    __syncthreads();

    if (tid >= 64) {
        // offload group nFull-1 (its buf data is final)
        int start = (nFull - 1) * span;
        int lane = tid - 64;
        int end = nFull * span;
        for (int t = start + lane; t < end; t += 64)
            if (t >= 0 && t < n) y[t] = buf[t & 2047];
    } else {
        // tail chunks (direct-global, masked, writes y itself)
        for (int c = nFull * 8; c < nIter; ++c) {
            int base = c * D;
            float4 qa = gx[base + tid];
            float4 qb = gx[base + 64 + tid];
            int t0 = base + tid;
            int t1 = t0 + 64;
            unsigned int s0 = __float_as_uint(qa.w);
            unsigned int s1 = __float_as_uint(qb.w);
            float a3 = buf[s0];
            float a2 = buf[s0 + 1];
            float a1 = buf[s0 + 2];
            float b3 = buf[s1];
            float b2 = buf[s1 + 1];
            float b1 = buf[s1 + 2];
            float ya = qa.x * a1;
            ya = fmaf(qa.y, a2, ya);
            ya = fmaf(qa.z, a3, ya);
            float yb = qb.x * b1;
            yb = fmaf(qb.y, b2, yb);
            yb = fmaf(qb.z, b3, yb);
            bool ok0 = on0 && (t0 < n);
            bool ok1 = on1 && (t1 < n);
            int w0 = t0 & 2047;
            int w1 = t1 & 2047;
            buf[ok0 ? w0 : 2050] = ya;
            buf[ok1 ? w1 : 2051] = yb;
            buf[(ok0 && w0 < 2) ? 2048 + w0 : 2050] = ya;
            buf[(ok1 && w1 < 2) ? 2048 + w1 : 2051] = yb;
            if (ok0) y[t0] = ya;
            if (ok1) y[t1] = yb;
        }
    }
#undef PRODUCE
#undef CBODY
}

// ---------------------------------------------------------------------------
extern "C" void kernel_launch(void* const* d_in, const int* in_sizes, int n_in,
                              void* d_out, int out_size, void* d_ws, size_t ws_size,
                              hipStream_t stream) {
    const float* delay = (const float*)d_in[0];
    const float* raw   = (const float*)d_in[1];
    const float* exc   = (const float*)d_in[2];
    int nf = in_sizes[0];
    int burst = in_sizes[2];
    if (burst > 2048) burst = 2048;
    int n = out_size;
    int nTot = n + 4096;   // pad covers producer prefetch overshoot (<= 2 group spans + chunk)

    char* ws = (char*)d_ws;
    size_t coefBytes = (size_t)3 * (nf - 1) * 4 * sizeof(double);
    size_t off = (coefBytes + 255) & ~(size_t)255;
    double* coef = (double*)ws;
    int* minz = (int*)(ws + off);
    off += 256;
    float* sink = (float*)(ws + off);
    off += 4096;
    float4* gxa = (float4*)(ws + off);

    size_t shmem = (size_t)(7 * nf) * sizeof(double);
    spline_setup<<<1, 64, shmem, stream>>>(delay, raw, coef, minz, nf);
    eval_kernel<<<(nTot + 255) / 256, 256, 0, stream>>>(coef, gxa, minz, n, nTot, nf);
    scan_kernel<<<1, 128, 0, stream>>>(gxa, minz, exc, (float*)d_out, sink, n, burst);
}